// Round 10
// baseline (753.820 us; speedup 1.0000x reference)
//
#include <hip/hip_runtime.h>
#include <stdint.h>

// Problem dims
#define HDIM   1024
#define BDIM   128
#define TSTEPS 128
#define DDIM   256
#define ODIM   1024
#define NSLOT  8      // hbuf rotation depth -> acquire fence only every 8th step

// Workspace byte offsets
// group counters cnt[grp][j] @ grp*1024 + j*128 (grp=0..3, j=0..7, ends 4096);
// grid counter cnt2[j] @ 4096 + j*128 (ends 4608). All < 8192, zeroed by the memset.
#define WS_CNT   0
#define WS_CNT2  4096
#define WS_HBUF  8192                                  // ushort [NSLOT][128][1024]
#define WS_HFIN  (WS_HBUF + NSLOT*BDIM*HDIM*2)         // float  [128][1024]
#define WS_PBUF  (WS_HFIN + BDIM*HDIM*4)               // float  [128][1024]
#define WS_WHHI  (WS_PBUF + BDIM*ODIM*4)               // ushort [4096][1024]
#define WS_WHLO  (WS_WHHI + 4*HDIM*HDIM*2)             // ushort [4096][1024]
#define WS_WXHI  (WS_WHLO + 4*HDIM*HDIM*2)             // ushort [4096][256]
#define WS_XT    (WS_WXHI + 4*HDIM*DDIM*2)             // ushort [128][128][256]

// LDS: h-tile stage + K-partial reduction buffer (dynamic shared, ~100KB, 1 block/CU)
// sH[32][HROW]: HROW=1032 shorts (pad 8 -> row rotation 4 banks; b128 A-frag reads
//   land 8 dwords/bank = conflict-free minimum).
// sG[4][32][SROW]: SROW=66 -> scatter banks (8*fg+fr)%32, max 2-way (free).
#define HROW 1032
#define SROW 66
#define SMEM_SH_BYTES (32*HROW*2)                       // 66,048
#define SMEM_BYTES    (SMEM_SH_BYTES + 4*32*SROW*4)     // 99,840

typedef __attribute__((ext_vector_type(8))) short frag8;
typedef __attribute__((ext_vector_type(4))) float f32x4;
typedef unsigned long long u64;

__device__ __forceinline__ unsigned short f2bf(float f) {
  union { float f; unsigned u; } v; v.f = f;
  unsigned r = v.u + 0x7fffu + ((v.u >> 16) & 1u);   // RNE
  return (unsigned short)(r >> 16);
}
__device__ __forceinline__ float bf2f(unsigned short h) {
  union { unsigned u; float f; } v; v.u = ((unsigned)h) << 16;
  return v.f;
}
__device__ __forceinline__ float sigm(float x) { return 1.f / (1.f + __expf(-x)); }
__device__ __forceinline__ float tanh_f(float x) {
  x = fminf(fmaxf(x, -20.f), 20.f);
  float e = __expf(2.f * x);
  return (e - 1.f) / (e + 1.f);
}

// Coherence idiom (gfx950, non-coherent per-XCD L2) — R2/R5/R8-validated, R10 refinement:
//  - producers: relaxed AGENT atomic stores (write-through to LLC; L2 never dirty).
//    R10: h values PACKED 4-wide via shuffles -> one 8B atomic store per 4 cols
//    (4x fewer LLC transactions than per-value 2B stores; atomics don't coalesce).
//  - release: __syncthreads() drains vmcnt(0) before tid0's arrive-add
//  - consumers: tid0 relaxed poll of monotone arrival counters (8 lines/group);
//    hbuf rotates over 8 slots; ONE acquire fence (tid0) every 8th step.
__device__ __forceinline__ void st_agent_f32(float* p, float v) {
  __hip_atomic_store(p, v, __ATOMIC_RELAXED, __HIP_MEMORY_SCOPE_AGENT);
}
__device__ __forceinline__ void st_agent_u64(u64* p, u64 v) {
  __hip_atomic_store(p, v, __ATOMIC_RELAXED, __HIP_MEMORY_SCOPE_AGENT);
}
// Direct global->LDS DMA, 16B per lane (LDS dest wave-uniform; HW adds lane*16).
__device__ __forceinline__ void gload_lds16(const unsigned short* g, unsigned short* l) {
  __builtin_amdgcn_global_load_lds(
      (const __attribute__((address_space(1))) unsigned int*)(g),
      (__attribute__((address_space(3))) unsigned int*)(l),
      16, 0, 0);
}

// ---------------- prep: fp32 -> bf16 (hi/lo) reformat + x transpose (unchanged) ------------
__global__ void prep_kernel(const float* __restrict__ Wh, const float* __restrict__ Wx,
                            const float* __restrict__ x, unsigned char* __restrict__ ws)
{
  unsigned short* whhi = (unsigned short*)(ws + WS_WHHI);
  unsigned short* whlo = (unsigned short*)(ws + WS_WHLO);
  unsigned short* wxhi = (unsigned short*)(ws + WS_WXHI);
  unsigned short* xt   = (unsigned short*)(ws + WS_XT);
  const int NWH = 4*HDIM*HDIM/4;       // 1,048,576 float4 items
  const int NWX = 4*HDIM*DDIM/4;       //   262,144
  const int NX  = BDIM*TSTEPS*DDIM/4;  // 1,048,576
  int stride = gridDim.x * blockDim.x;
  for (int i = blockIdx.x*blockDim.x + threadIdx.x; i < NWH+NWX+NX; i += stride) {
    if (i < NWH) {
      float4 w = ((const float4*)Wh)[i];
      ushort4 hi, lo;
      hi.x = f2bf(w.x); lo.x = f2bf(w.x - bf2f(hi.x));
      hi.y = f2bf(w.y); lo.y = f2bf(w.y - bf2f(hi.y));
      hi.z = f2bf(w.z); lo.z = f2bf(w.z - bf2f(hi.z));
      hi.w = f2bf(w.w); lo.w = f2bf(w.w - bf2f(hi.w));
      ((ushort4*)whhi)[i] = hi;
      ((ushort4*)whlo)[i] = lo;
    } else if (i < NWH + NWX) {
      int j = i - NWH;
      float4 w = ((const float4*)Wx)[j];
      ushort4 hi;
      hi.x = f2bf(w.x); hi.y = f2bf(w.y); hi.z = f2bf(w.z); hi.w = f2bf(w.w);
      ((ushort4*)wxhi)[j] = hi;
    } else {
      int j = i - NWH - NWX;           // x flat [b][t][dv]
      int dv = j & 63;
      int t  = (j >> 6) & (TSTEPS - 1);
      int b  = j >> 13;
      float4 w = ((const float4*)x)[j];
      ushort4 hv;
      hv.x = f2bf(w.x); hv.y = f2bf(w.y); hv.z = f2bf(w.z); hv.w = f2bf(w.w);
      ((ushort4*)xt)[((size_t)t*BDIM + b)*64 + dv] = hv;   // xT[t][b][d]
    }
  }
}

// ---------------- persistent LSTM kernel (cooperative, 256 blocks x 512 thr) ----------------
// Block (mh = blockIdx&3, nsl = blockIdx>>2): batch rows [mh*32,+32), h-cols [nsl*16,+16).
// 8 waves = (wn: gate pair) x (wk: K-quarter). Weights in REGISTERS (pinned, ~144 regs).
// h-tile staged cooperatively into LDS via global_load_lds (R5/R8/R9 structure).
// R10 change (single): h-publish packed -- each 4 adjacent cols (same row, adjacent
// lanes) are gathered via 2 shuffles and stored as ONE 8B agent atomic store by the
// lane&3==0 lane. 512 x 2B tx/block/step -> 128 x 8B tx (atomics don't coalesce;
// transaction count was the hidden critical-path cost).
__global__ void __launch_bounds__(512, 2)
lstm_main(const float* __restrict__ bx, const float* __restrict__ Wp,
          const float* __restrict__ bp, unsigned char* __restrict__ ws,
          float* __restrict__ out)
{
  extern __shared__ unsigned char smem[];
  unsigned short* sH = (unsigned short*)smem;                          // [32][HROW]
  float (*sG)[32][SROW] = (float (*)[32][SROW])(smem + SMEM_SH_BYTES); // [4][32][SROW]

  unsigned short* hbuf = (unsigned short*)(ws + WS_HBUF);
  float*          hfin = (float*)(ws + WS_HFIN);
  float*          pbuf = (float*)(ws + WS_PBUF);
  const unsigned short* whhi = (const unsigned short*)(ws + WS_WHHI);
  const unsigned short* whlo = (const unsigned short*)(ws + WS_WHLO);
  const unsigned short* wxhi = (const unsigned short*)(ws + WS_WXHI);
  const unsigned short* xt   = (const unsigned short*)(ws + WS_XT);

  const int tid  = threadIdx.x;
  const int lane = tid & 63;
  const int wv   = tid >> 6;      // wave 0..7
  const int wn   = wv >> 2;       // gate pair: gates {wn*2, wn*2+1}
  const int wk   = wv & 3;        // K quarter: H cols [wk*256,+256), D cols [wk*64,+64)
  const int fr   = lane & 15;     // MFMA frag row (m for A, n for B)
  const int fg   = lane >> 4;     // k-group 0..3
  const int mh   = blockIdx.x & 3;
  const int nsl  = blockIdx.x >> 2;    // 0..63
  const int hc0  = nsl << 4;           // 16 h-cols
  const int m0   = mh << 5;            // 32 batch rows

  // barrier plumbing: 8 arrival lines per group (64 blocks/group) + 4 grid lines
  unsigned* cntg = (unsigned*)(ws + WS_CNT + (size_t)mh*1024);  // [j]*32 words (128B lines)
  unsigned* cnt2 = (unsigned*)(ws + WS_CNT2);
  const int  jln = nsl & 7;

  // ---- preload this wave's weight fragments into registers (once, time-invariant) ----
  frag8 whi_[2][8], wlo_[2][8], wx_[2][2];
  #pragma unroll
  for (int nt = 0; nt < 2; ++nt) {
    const int g = wn*2 + nt;
    const size_t grow = (size_t)g*HDIM + hc0 + fr;
    const unsigned short* ph = whhi + grow*HDIM + wk*256 + fg*8;
    const unsigned short* pl = whlo + grow*HDIM + wk*256 + fg*8;
    #pragma unroll
    for (int kc = 0; kc < 8; ++kc) {
      whi_[nt][kc] = *(const frag8*)(ph + kc*32);
      wlo_[nt][kc] = *(const frag8*)(pl + kc*32);
    }
    const unsigned short* px = wxhi + grow*DDIM + wk*64 + fg*8;
    #pragma unroll
    for (int kc = 0; kc < 2; ++kc)
      wx_[nt][kc] = *(const frag8*)(px + kc*32);
  }
  // Pin: keep values opaque (register-resident; cannot be re-formed from memory).
  #pragma unroll
  for (int nt = 0; nt < 2; ++nt) {
    #pragma unroll
    for (int kc = 0; kc < 8; ++kc)
      asm volatile("" : "+v"(whi_[nt][kc]), "+v"(wlo_[nt][kc]));
    #pragma unroll
    for (int kc = 0; kc < 2; ++kc)
      asm volatile("" : "+v"(wx_[nt][kc]));
  }

  // update-phase mapping: one (row,col) item per thread; biases hoisted
  const int uj  = tid & 15;                       // h-col within 16 (== lane&15)
  const int um  = tid >> 4;                       // row within 32 (0..31)
  const float bg = bx[0*HDIM + hc0 + uj];
  const float bi = bx[1*HDIM + hc0 + uj];
  const float bf = bx[2*HDIM + hc0 + uj];
  const float bo = bx[3*HDIM + hc0 + uj];

  float c = 0.f;
  const int arow0 = m0 + fr;                      // global batch row of A-frag (mt=0)

  for (int t = 0; t < TSTEPS; ++t) {
    f32x4 zero4 = {0.f, 0.f, 0.f, 0.f};
    f32x4 acc[2][2];                              // [mt][nt] K-partials
    acc[0][0] = zero4; acc[0][1] = zero4; acc[1][0] = zero4; acc[1][1] = zero4;

    // ---- issue x-frag loads NOW (depend on nothing; overlap poll + stage DMA) ----
    frag8 xa[2][2];
    {
      const unsigned short* xb = xt + ((size_t)t*BDIM + arow0)*DDIM + wk*64 + fg*8;
      #pragma unroll
      for (int kc = 0; kc < 2; ++kc)
        #pragma unroll
        for (int mt = 0; mt < 2; ++mt)
          xa[mt][kc] = *(const frag8*)(xb + (size_t)mt*16*DDIM + kc*32);
    }

    // ---- wait: h_t published for this group (sum of arrivals >= 64*t) ----
    if (tid == 0) {
      if (t) {
        const unsigned tgt = 64u * (unsigned)t;
        for (;;) {
          unsigned s = 0;
          #pragma unroll
          for (int j = 0; j < 8; ++j)
            s += __hip_atomic_load(cntg + j*32, __ATOMIC_RELAXED, __HIP_MEMORY_SCOPE_AGENT);
          if (s >= tgt) break;
          __builtin_amdgcn_s_sleep(1);
        }
      }
      // acquire fence only when the slot rotation wraps: exactly one inv between
      // consecutive uses of any slot address; keeps hbuf/xt L2-resident otherwise.
      if ((t & 7) == 0)
        __builtin_amdgcn_fence(__ATOMIC_ACQUIRE, "agent");
    }
    __syncthreads();

    // ---- stage h-tile (32 rows x 1024 cols) into LDS: 64 chunks x 1024B, all in flight ----
    {
      const unsigned short* hsrc = hbuf + ((size_t)(t & 7)*BDIM + m0)*HDIM;
      #pragma unroll
      for (int it = 0; it < 8; ++it) {
        const int ci  = wv*8 + it;            // chunk 0..63 (wave-uniform)
        const int row = ci >> 1, half = ci & 1;
        gload_lds16(hsrc + (size_t)row*HDIM + half*512 + lane*8,
                    sH + row*HROW + half*512);
      }
    }

    // ---- x-path MFMAs: xa loads are OLDER than the DMA in vmcnt order, so these
    //      run while the 8 wave-DMAs are still in flight ----
    {
      #pragma unroll
      for (int kc = 0; kc < 2; ++kc) {
        #pragma unroll
        for (int mt = 0; mt < 2; ++mt) {
          acc[mt][0] = __builtin_amdgcn_mfma_f32_16x16x32_bf16(xa[mt][kc], wx_[0][kc], acc[mt][0], 0, 0, 0);
          acc[mt][1] = __builtin_amdgcn_mfma_f32_16x16x32_bf16(xa[mt][kc], wx_[1][kc], acc[mt][1], 0, 0, 0);
        }
      }
    }
    __syncthreads();   // drains global_load_lds vmcnt; sH ready

    // ---- h-path: K-partial gates += h_t[,K-slice] @ (Wh_hi + Wh_lo)^T (LDS reads) ----
    {
      const unsigned short* hb = sH + wk*256 + fg*8;
      #pragma unroll
      for (int kc = 0; kc < 8; ++kc) {
        frag8 a0 = *(const frag8*)(hb + fr*HROW        + kc*32);
        frag8 a1 = *(const frag8*)(hb + (16 + fr)*HROW + kc*32);
        acc[0][0] = __builtin_amdgcn_mfma_f32_16x16x32_bf16(a0, whi_[0][kc], acc[0][0], 0, 0, 0);
        acc[0][1] = __builtin_amdgcn_mfma_f32_16x16x32_bf16(a0, whi_[1][kc], acc[0][1], 0, 0, 0);
        acc[1][0] = __builtin_amdgcn_mfma_f32_16x16x32_bf16(a1, whi_[0][kc], acc[1][0], 0, 0, 0);
        acc[1][1] = __builtin_amdgcn_mfma_f32_16x16x32_bf16(a1, whi_[1][kc], acc[1][1], 0, 0, 0);
        acc[0][0] = __builtin_amdgcn_mfma_f32_16x16x32_bf16(a0, wlo_[0][kc], acc[0][0], 0, 0, 0);
        acc[0][1] = __builtin_amdgcn_mfma_f32_16x16x32_bf16(a0, wlo_[1][kc], acc[0][1], 0, 0, 0);
        acc[1][0] = __builtin_amdgcn_mfma_f32_16x16x32_bf16(a1, wlo_[0][kc], acc[1][0], 0, 0, 0);
        acc[1][1] = __builtin_amdgcn_mfma_f32_16x16x32_bf16(a1, wlo_[1][kc], acc[1][1], 0, 0, 0);
      }
    }

    // ---- scatter K-partials to LDS (C/D layout: col=lane&15, row=(lane>>4)*4+reg) ----
    {
      float (*sGw)[SROW] = sG[wk];
      #pragma unroll
      for (int mt = 0; mt < 2; ++mt)
        #pragma unroll
        for (int nt = 0; nt < 2; ++nt)
          #pragma unroll
          for (int r = 0; r < 4; ++r)
            sGw[mt*16 + fg*4 + r][(wn*2 + nt)*16 + fr] = acc[mt][nt][r];
    }
    __syncthreads();

    // ---- K-reduce + gate nonlinearities + state update (c stays in registers) ----
    {
      float gg = bg, gi = bi, gf = bf, go = bo;
      #pragma unroll
      for (int q = 0; q < 4; ++q) {
        gg += sG[q][um][uj];
        gi += sG[q][um][16 + uj];
        gf += sG[q][um][32 + uj];
        go += sG[q][um][48 + uj];
      }
      c = tanh_f(gg)*sigm(gi) + c*sigm(gf);
      float h = tanh_f(c)*sigm(go);

      // ---- packed h-publish: 4 adjacent cols (lanes l..l+3, same row) -> one 8B
      //      agent atomic store from lane&3==0. 4x fewer LLC transactions. ----
      unsigned hv = (unsigned)f2bf(h);
      unsigned p2 = hv | (__shfl_down(hv, 1) << 16);
      u64 p4 = (u64)p2 | ((u64)__shfl_down(p2, 2) << 32);
      if ((lane & 3) == 0) {
        unsigned short* hw = hbuf + (size_t)((t + 1) & 7)*BDIM*HDIM;
        st_agent_u64((u64*)(hw + (size_t)(m0 + um)*HDIM + hc0 + uj), p4);
      }
      if (t == TSTEPS - 1)
        st_agent_f32(hfin + (size_t)(m0 + um)*HDIM + hc0 + uj, h);
    }

    // ---- arrive: syncthreads drains vmcnt(0) (release), then add ----
    __syncthreads();
    if (tid == 0)
      __hip_atomic_fetch_add(cntg + jln*32, 1u, __ATOMIC_RELAXED, __HIP_MEMORY_SCOPE_AGENT);
  }

  // ---- wait: own group finished all steps (hfin complete for our rows) ----
  if (tid == 0) {
    const unsigned tgt = 64u * (unsigned)TSTEPS;
    for (;;) {
      unsigned s = 0;
      #pragma unroll
      for (int j = 0; j < 8; ++j)
        s += __hip_atomic_load(cntg + j*32, __ATOMIC_RELAXED, __HIP_MEMORY_SCOPE_AGENT);
      if (s >= tgt) break;
      __builtin_amdgcn_s_sleep(1);
    }
    __builtin_amdgcn_fence(__ATOMIC_ACQUIRE, "agent");   // one-shot inv: hfin readable
  }
  __syncthreads();

  // ---- projection: p = h_last @ Wp^T + bp (1 item/thread: [m0+um] x [hc0+uj]) ----
  {
    const int m = m0 + um, n = hc0 + uj;
    const float4* hr = (const float4*)(hfin + (size_t)m*HDIM);
    const float4* wr = (const float4*)(Wp + (size_t)n*HDIM);
    float s = 0.f;
    #pragma unroll 4
    for (int k = 0; k < HDIM/4; ++k) {
      float4 a = hr[k], b = wr[k];
      s += a.x*b.x + a.y*b.y + a.z*b.z + a.w*b.w;
    }
    st_agent_f32(&pbuf[(size_t)m*ODIM + n], s + bp[n]);
  }

  // ---- one-shot full-grid barrier (pbuf complete), then softmax on blocks < 128 ----
  __syncthreads();
  if (tid == 0)
    __hip_atomic_fetch_add(cnt2 + (jln & 3)*32, 1u, __ATOMIC_RELAXED, __HIP_MEMORY_SCOPE_AGENT);

  if (blockIdx.x >= BDIM) return;

  if (tid == 0) {
    for (;;) {
      unsigned s = 0;
      #pragma unroll
      for (int j = 0; j < 4; ++j)
        s += __hip_atomic_load(cnt2 + j*32, __ATOMIC_RELAXED, __HIP_MEMORY_SCOPE_AGENT);
      if (s >= 256u) break;
      __builtin_amdgcn_s_sleep(1);
    }
    __builtin_amdgcn_fence(__ATOMIC_ACQUIRE, "agent");  // one-shot inv: pbuf readable
  }
  __syncthreads();

  // ---- softmax: one block per batch row (512 thr x float2) ----
  {
    int b = blockIdx.x;
    float* sF = (float*)smem;
    float2 v = ((const float2*)(pbuf + (size_t)b*ODIM))[tid];
    float mx = fmaxf(v.x, v.y);
    #pragma unroll
    for (int off = 32; off > 0; off >>= 1)
      mx = fmaxf(mx, __shfl_xor(mx, off, 64));
    if (lane == 0) sF[wv] = mx;
    __syncthreads();
    mx = sF[0];
    #pragma unroll
    for (int i = 1; i < 8; ++i) mx = fmaxf(mx, sF[i]);
    float e0 = __expf(v.x - mx), e1 = __expf(v.y - mx);
    float s = e0 + e1;
    #pragma unroll
    for (int off = 32; off > 0; off >>= 1)
      s += __shfl_xor(s, off, 64);
    if (lane == 0) sF[8 + wv] = s;
    __syncthreads();
    s = sF[8];
    #pragma unroll
    for (int i = 1; i < 8; ++i) s += sF[8 + i];
    float inv = 1.f / s;
    float2 o; o.x = e0*inv; o.y = e1*inv;
    ((float2*)(out + (size_t)b*ODIM))[tid] = o;
  }
}

// ---------------- host launch ----------------
extern "C" void kernel_launch(void* const* d_in, const int* in_sizes, int n_in,
                              void* d_out, int out_size, void* d_ws, size_t ws_size,
                              hipStream_t stream) {
  (void)in_sizes; (void)n_in; (void)out_size; (void)ws_size;
  const float* x  = (const float*)d_in[0];
  const float* Wx = (const float*)d_in[1];
  const float* bx = (const float*)d_in[2];
  const float* Wh = (const float*)d_in[3];
  const float* Wp = (const float*)d_in[4];
  const float* bp = (const float*)d_in[5];
  float* out = (float*)d_out;
  unsigned char* ws = (unsigned char*)d_ws;

  // zero control block (counters) + h0 slot 0
  hipMemsetAsync(ws, 0, WS_HBUF + BDIM*HDIM*2, stream);

  hipLaunchKernelGGL(prep_kernel, dim3(1024), dim3(256), 0, stream, Wh, Wx, x, ws);

  hipFuncSetAttribute(reinterpret_cast<const void*>(&lstm_main),
                      hipFuncAttributeMaxDynamicSharedMemorySize, SMEM_BYTES);
  void* args[5];
  args[0] = (void*)&bx; args[1] = (void*)&Wp; args[2] = (void*)&bp;
  args[3] = (void*)&ws; args[4] = (void*)&out;
  hipLaunchCooperativeKernel(reinterpret_cast<const void*>(&lstm_main),
                             dim3(256), dim3(512), args, SMEM_BYTES, stream);
}

// Round 11
// 721.311 us; speedup vs baseline: 1.0451x; 1.0451x over previous
//
#include <hip/hip_runtime.h>
#include <stdint.h>

// Problem dims
#define HDIM   1024
#define BDIM   128
#define TSTEPS 128
#define DDIM   256
#define ODIM   1024
#define NSLOT  32     // hbuf rotation depth -> acquire fence only every 32nd step
#define SLOTM  (NSLOT - 1)

// Workspace byte offsets
// group counters cnt[grp][j] @ grp*1024 + j*128 (grp=0..3, j=0..7, ends 4096);
// grid counter cnt2[j] @ 4096 + j*128 (ends 4608). All < 8192, zeroed by the memset.
#define WS_CNT   0
#define WS_CNT2  4096
#define WS_HBUF  8192                                  // ushort [NSLOT][128][1024]
#define WS_HFIN  (WS_HBUF + (size_t)NSLOT*BDIM*HDIM*2) // float  [128][1024]
#define WS_PBUF  (WS_HFIN + BDIM*HDIM*4)               // float  [128][1024]
#define WS_WHHI  (WS_PBUF + BDIM*ODIM*4)               // ushort [4096][1024]
#define WS_WHLO  (WS_WHHI + 4*HDIM*HDIM*2)             // ushort [4096][1024]
#define WS_WXHI  (WS_WHLO + 4*HDIM*HDIM*2)             // ushort [4096][256]
#define WS_XT    (WS_WXHI + 4*HDIM*DDIM*2)             // ushort [128][128][256]

// LDS: h-tile stage + K-partial reduction buffer (dynamic shared, ~100KB, 1 block/CU)
// sH[32][HROW]: HROW=1032 shorts (pad 8 -> row rotation 4 banks; b128 A-frag reads
//   land 8 dwords/bank = conflict-free minimum).
// sG[4][32][SROW]: SROW=66 -> scatter banks (8*fg+fr)%32, max 2-way (free).
#define HROW 1032
#define SROW 66
#define SMEM_SH_BYTES (32*HROW*2)                       // 66,048
#define SMEM_BYTES    (SMEM_SH_BYTES + 4*32*SROW*4)     // 99,840

typedef __attribute__((ext_vector_type(8))) short frag8;
typedef __attribute__((ext_vector_type(4))) float f32x4;

__device__ __forceinline__ unsigned short f2bf(float f) {
  union { float f; unsigned u; } v; v.f = f;
  unsigned r = v.u + 0x7fffu + ((v.u >> 16) & 1u);   // RNE
  return (unsigned short)(r >> 16);
}
__device__ __forceinline__ float bf2f(unsigned short h) {
  union { unsigned u; float f; } v; v.u = ((unsigned)h) << 16;
  return v.f;
}
__device__ __forceinline__ float sigm(float x) { return 1.f / (1.f + __expf(-x)); }
__device__ __forceinline__ float tanh_f(float x) {
  x = fminf(fmaxf(x, -20.f), 20.f);
  float e = __expf(2.f * x);
  return (e - 1.f) / (e + 1.f);
}

// Coherence idiom (gfx950, non-coherent per-XCD L2) — R2/R5/R8-validated, R11 refinement:
//  - producers: relaxed AGENT atomic stores (write-through to LLC; L2 never dirty).
//    (R10's 8B-packed stores were NEUTRAL-to-worse: transaction count is not the
//    bottleneck -- reverted to per-element 2B stores.)
//  - release: __syncthreads() drains vmcnt(0) before tid0's arrive-add
//  - consumers: tid0 relaxed poll of monotone arrival counters (8 lines/group);
//    hbuf rotates over 32 slots; ONE acquire fence (tid0) every 32nd step.
//    Every slot address is reused only every 32 steps and exactly one fence lies
//    between consecutive uses -> no stale L2 line can be consumed; skew < 1 << 32.
__device__ __forceinline__ void st_agent_u16(unsigned short* p, unsigned short v) {
  __hip_atomic_store(p, v, __ATOMIC_RELAXED, __HIP_MEMORY_SCOPE_AGENT);
}
__device__ __forceinline__ void st_agent_f32(float* p, float v) {
  __hip_atomic_store(p, v, __ATOMIC_RELAXED, __HIP_MEMORY_SCOPE_AGENT);
}
// Direct global->LDS DMA, 16B per lane (LDS dest wave-uniform; HW adds lane*16).
__device__ __forceinline__ void gload_lds16(const unsigned short* g, unsigned short* l) {
  __builtin_amdgcn_global_load_lds(
      (const __attribute__((address_space(1))) unsigned int*)(g),
      (__attribute__((address_space(3))) unsigned int*)(l),
      16, 0, 0);
}

// ---------------- prep: fp32 -> bf16 (hi/lo) reformat + x transpose (unchanged) ------------
__global__ void prep_kernel(const float* __restrict__ Wh, const float* __restrict__ Wx,
                            const float* __restrict__ x, unsigned char* __restrict__ ws)
{
  unsigned short* whhi = (unsigned short*)(ws + WS_WHHI);
  unsigned short* whlo = (unsigned short*)(ws + WS_WHLO);
  unsigned short* wxhi = (unsigned short*)(ws + WS_WXHI);
  unsigned short* xt   = (unsigned short*)(ws + WS_XT);
  const int NWH = 4*HDIM*HDIM/4;       // 1,048,576 float4 items
  const int NWX = 4*HDIM*DDIM/4;       //   262,144
  const int NX  = BDIM*TSTEPS*DDIM/4;  // 1,048,576
  int stride = gridDim.x * blockDim.x;
  for (int i = blockIdx.x*blockDim.x + threadIdx.x; i < NWH+NWX+NX; i += stride) {
    if (i < NWH) {
      float4 w = ((const float4*)Wh)[i];
      ushort4 hi, lo;
      hi.x = f2bf(w.x); lo.x = f2bf(w.x - bf2f(hi.x));
      hi.y = f2bf(w.y); lo.y = f2bf(w.y - bf2f(hi.y));
      hi.z = f2bf(w.z); lo.z = f2bf(w.z - bf2f(hi.z));
      hi.w = f2bf(w.w); lo.w = f2bf(w.w - bf2f(hi.w));
      ((ushort4*)whhi)[i] = hi;
      ((ushort4*)whlo)[i] = lo;
    } else if (i < NWH + NWX) {
      int j = i - NWH;
      float4 w = ((const float4*)Wx)[j];
      ushort4 hi;
      hi.x = f2bf(w.x); hi.y = f2bf(w.y); hi.z = f2bf(w.z); hi.w = f2bf(w.w);
      ((ushort4*)wxhi)[j] = hi;
    } else {
      int j = i - NWH - NWX;           // x flat [b][t][dv]
      int dv = j & 63;
      int t  = (j >> 6) & (TSTEPS - 1);
      int b  = j >> 13;
      float4 w = ((const float4*)x)[j];
      ushort4 hv;
      hv.x = f2bf(w.x); hv.y = f2bf(w.y); hv.z = f2bf(w.z); hv.w = f2bf(w.w);
      ((ushort4*)xt)[((size_t)t*BDIM + b)*64 + dv] = hv;   // xT[t][b][d]
    }
  }
}

// ---------------- persistent LSTM kernel (cooperative, 256 blocks x 512 thr) ----------------
// Block (mh = blockIdx&3, nsl = blockIdx>>2): batch rows [mh*32,+32), h-cols [nsl*16,+16).
// 8 waves = (wn: gate pair) x (wk: K-quarter). Weights in REGISTERS (pinned, ~144 regs).
// h-tile staged cooperatively into LDS via global_load_lds (R5/R8/R9 structure).
// R11 change (single): NSLOT=32 -> only 4 in-loop fences total (each full-L2 inv costs
// ~1.7us of group-wide LLC refetch); h-publish back to per-element 2B stores (R10's
// packing was neutral-to-worse).
__global__ void __launch_bounds__(512, 2)
lstm_main(const float* __restrict__ bx, const float* __restrict__ Wp,
          const float* __restrict__ bp, unsigned char* __restrict__ ws,
          float* __restrict__ out)
{
  extern __shared__ unsigned char smem[];
  unsigned short* sH = (unsigned short*)smem;                          // [32][HROW]
  float (*sG)[32][SROW] = (float (*)[32][SROW])(smem + SMEM_SH_BYTES); // [4][32][SROW]

  unsigned short* hbuf = (unsigned short*)(ws + WS_HBUF);
  float*          hfin = (float*)(ws + WS_HFIN);
  float*          pbuf = (float*)(ws + WS_PBUF);
  const unsigned short* whhi = (const unsigned short*)(ws + WS_WHHI);
  const unsigned short* whlo = (const unsigned short*)(ws + WS_WHLO);
  const unsigned short* wxhi = (const unsigned short*)(ws + WS_WXHI);
  const unsigned short* xt   = (const unsigned short*)(ws + WS_XT);

  const int tid  = threadIdx.x;
  const int lane = tid & 63;
  const int wv   = tid >> 6;      // wave 0..7
  const int wn   = wv >> 2;       // gate pair: gates {wn*2, wn*2+1}
  const int wk   = wv & 3;        // K quarter: H cols [wk*256,+256), D cols [wk*64,+64)
  const int fr   = lane & 15;     // MFMA frag row (m for A, n for B)
  const int fg   = lane >> 4;     // k-group 0..3
  const int mh   = blockIdx.x & 3;
  const int nsl  = blockIdx.x >> 2;    // 0..63
  const int hc0  = nsl << 4;           // 16 h-cols
  const int m0   = mh << 5;            // 32 batch rows

  // barrier plumbing: 8 arrival lines per group (64 blocks/group) + 4 grid lines
  unsigned* cntg = (unsigned*)(ws + WS_CNT + (size_t)mh*1024);  // [j]*32 words (128B lines)
  unsigned* cnt2 = (unsigned*)(ws + WS_CNT2);
  const int  jln = nsl & 7;

  // ---- preload this wave's weight fragments into registers (once, time-invariant) ----
  frag8 whi_[2][8], wlo_[2][8], wx_[2][2];
  #pragma unroll
  for (int nt = 0; nt < 2; ++nt) {
    const int g = wn*2 + nt;
    const size_t grow = (size_t)g*HDIM + hc0 + fr;
    const unsigned short* ph = whhi + grow*HDIM + wk*256 + fg*8;
    const unsigned short* pl = whlo + grow*HDIM + wk*256 + fg*8;
    #pragma unroll
    for (int kc = 0; kc < 8; ++kc) {
      whi_[nt][kc] = *(const frag8*)(ph + kc*32);
      wlo_[nt][kc] = *(const frag8*)(pl + kc*32);
    }
    const unsigned short* px = wxhi + grow*DDIM + wk*64 + fg*8;
    #pragma unroll
    for (int kc = 0; kc < 2; ++kc)
      wx_[nt][kc] = *(const frag8*)(px + kc*32);
  }
  // Pin: keep values opaque (register-resident; cannot be re-formed from memory).
  #pragma unroll
  for (int nt = 0; nt < 2; ++nt) {
    #pragma unroll
    for (int kc = 0; kc < 8; ++kc)
      asm volatile("" : "+v"(whi_[nt][kc]), "+v"(wlo_[nt][kc]));
    #pragma unroll
    for (int kc = 0; kc < 2; ++kc)
      asm volatile("" : "+v"(wx_[nt][kc]));
  }

  // update-phase mapping: one (row,col) item per thread; biases hoisted
  const int uj  = tid & 15;                       // h-col within 16
  const int um  = tid >> 4;                       // row within 32 (0..31)
  const float bg = bx[0*HDIM + hc0 + uj];
  const float bi = bx[1*HDIM + hc0 + uj];
  const float bf = bx[2*HDIM + hc0 + uj];
  const float bo = bx[3*HDIM + hc0 + uj];

  float c = 0.f;
  const int arow0 = m0 + fr;                      // global batch row of A-frag (mt=0)

  for (int t = 0; t < TSTEPS; ++t) {
    f32x4 zero4 = {0.f, 0.f, 0.f, 0.f};
    f32x4 acc[2][2];                              // [mt][nt] K-partials
    acc[0][0] = zero4; acc[0][1] = zero4; acc[1][0] = zero4; acc[1][1] = zero4;

    // ---- issue x-frag loads NOW (depend on nothing; overlap poll + stage DMA) ----
    frag8 xa[2][2];
    {
      const unsigned short* xb = xt + ((size_t)t*BDIM + arow0)*DDIM + wk*64 + fg*8;
      #pragma unroll
      for (int kc = 0; kc < 2; ++kc)
        #pragma unroll
        for (int mt = 0; mt < 2; ++mt)
          xa[mt][kc] = *(const frag8*)(xb + (size_t)mt*16*DDIM + kc*32);
    }

    // ---- wait: h_t published for this group (sum of arrivals >= 64*t) ----
    if (tid == 0) {
      if (t) {
        const unsigned tgt = 64u * (unsigned)t;
        for (;;) {
          unsigned s = 0;
          #pragma unroll
          for (int j = 0; j < 8; ++j)
            s += __hip_atomic_load(cntg + j*32, __ATOMIC_RELAXED, __HIP_MEMORY_SCOPE_AGENT);
          if (s >= tgt) break;
          __builtin_amdgcn_s_sleep(1);
        }
      }
      // acquire fence only when the slot rotation wraps (4 times total): exactly one
      // inv between consecutive uses of any slot address; hbuf/xt stay L2-resident.
      if ((t & SLOTM) == 0)
        __builtin_amdgcn_fence(__ATOMIC_ACQUIRE, "agent");
    }
    __syncthreads();

    // ---- stage h-tile (32 rows x 1024 cols) into LDS: 64 chunks x 1024B, all in flight ----
    {
      const unsigned short* hsrc = hbuf + ((size_t)(t & SLOTM)*BDIM + m0)*HDIM;
      #pragma unroll
      for (int it = 0; it < 8; ++it) {
        const int ci  = wv*8 + it;            // chunk 0..63 (wave-uniform)
        const int row = ci >> 1, half = ci & 1;
        gload_lds16(hsrc + (size_t)row*HDIM + half*512 + lane*8,
                    sH + row*HROW + half*512);
      }
    }

    // ---- x-path MFMAs: xa loads are OLDER than the DMA in vmcnt order, so these
    //      run while the 8 wave-DMAs are still in flight ----
    {
      #pragma unroll
      for (int kc = 0; kc < 2; ++kc) {
        #pragma unroll
        for (int mt = 0; mt < 2; ++mt) {
          acc[mt][0] = __builtin_amdgcn_mfma_f32_16x16x32_bf16(xa[mt][kc], wx_[0][kc], acc[mt][0], 0, 0, 0);
          acc[mt][1] = __builtin_amdgcn_mfma_f32_16x16x32_bf16(xa[mt][kc], wx_[1][kc], acc[mt][1], 0, 0, 0);
        }
      }
    }
    __syncthreads();   // drains global_load_lds vmcnt; sH ready

    // ---- h-path: K-partial gates += h_t[,K-slice] @ (Wh_hi + Wh_lo)^T (LDS reads) ----
    {
      const unsigned short* hb = sH + wk*256 + fg*8;
      #pragma unroll
      for (int kc = 0; kc < 8; ++kc) {
        frag8 a0 = *(const frag8*)(hb + fr*HROW        + kc*32);
        frag8 a1 = *(const frag8*)(hb + (16 + fr)*HROW + kc*32);
        acc[0][0] = __builtin_amdgcn_mfma_f32_16x16x32_bf16(a0, whi_[0][kc], acc[0][0], 0, 0, 0);
        acc[0][1] = __builtin_amdgcn_mfma_f32_16x16x32_bf16(a0, whi_[1][kc], acc[0][1], 0, 0, 0);
        acc[1][0] = __builtin_amdgcn_mfma_f32_16x16x32_bf16(a1, whi_[0][kc], acc[1][0], 0, 0, 0);
        acc[1][1] = __builtin_amdgcn_mfma_f32_16x16x32_bf16(a1, whi_[1][kc], acc[1][1], 0, 0, 0);
        acc[0][0] = __builtin_amdgcn_mfma_f32_16x16x32_bf16(a0, wlo_[0][kc], acc[0][0], 0, 0, 0);
        acc[0][1] = __builtin_amdgcn_mfma_f32_16x16x32_bf16(a0, wlo_[1][kc], acc[0][1], 0, 0, 0);
        acc[1][0] = __builtin_amdgcn_mfma_f32_16x16x32_bf16(a1, wlo_[0][kc], acc[1][0], 0, 0, 0);
        acc[1][1] = __builtin_amdgcn_mfma_f32_16x16x32_bf16(a1, wlo_[1][kc], acc[1][1], 0, 0, 0);
      }
    }

    // ---- scatter K-partials to LDS (C/D layout: col=lane&15, row=(lane>>4)*4+reg) ----
    {
      float (*sGw)[SROW] = sG[wk];
      #pragma unroll
      for (int mt = 0; mt < 2; ++mt)
        #pragma unroll
        for (int nt = 0; nt < 2; ++nt)
          #pragma unroll
          for (int r = 0; r < 4; ++r)
            sGw[mt*16 + fg*4 + r][(wn*2 + nt)*16 + fr] = acc[mt][nt][r];
    }
    __syncthreads();

    // ---- K-reduce + gate nonlinearities + state update (c stays in registers) ----
    {
      float gg = bg, gi = bi, gf = bf, go = bo;
      #pragma unroll
      for (int q = 0; q < 4; ++q) {
        gg += sG[q][um][uj];
        gi += sG[q][um][16 + uj];
        gf += sG[q][um][32 + uj];
        go += sG[q][um][48 + uj];
      }
      c = tanh_f(gg)*sigm(gi) + c*sigm(gf);
      float h = tanh_f(c)*sigm(go);

      unsigned short* hw = hbuf + (size_t)((t + 1) & SLOTM)*BDIM*HDIM;
      st_agent_u16(hw + (size_t)(m0 + um)*HDIM + hc0 + uj, f2bf(h));
      if (t == TSTEPS - 1)
        st_agent_f32(hfin + (size_t)(m0 + um)*HDIM + hc0 + uj, h);
    }

    // ---- arrive: syncthreads drains vmcnt(0) (release), then add ----
    __syncthreads();
    if (tid == 0)
      __hip_atomic_fetch_add(cntg + jln*32, 1u, __ATOMIC_RELAXED, __HIP_MEMORY_SCOPE_AGENT);
  }

  // ---- wait: own group finished all steps (hfin complete for our rows) ----
  if (tid == 0) {
    const unsigned tgt = 64u * (unsigned)TSTEPS;
    for (;;) {
      unsigned s = 0;
      #pragma unroll
      for (int j = 0; j < 8; ++j)
        s += __hip_atomic_load(cntg + j*32, __ATOMIC_RELAXED, __HIP_MEMORY_SCOPE_AGENT);
      if (s >= tgt) break;
      __builtin_amdgcn_s_sleep(1);
    }
    __builtin_amdgcn_fence(__ATOMIC_ACQUIRE, "agent");   // one-shot inv: hfin readable
  }
  __syncthreads();

  // ---- projection: p = h_last @ Wp^T + bp (1 item/thread: [m0+um] x [hc0+uj]) ----
  {
    const int m = m0 + um, n = hc0 + uj;
    const float4* hr = (const float4*)(hfin + (size_t)m*HDIM);
    const float4* wr = (const float4*)(Wp + (size_t)n*HDIM);
    float s = 0.f;
    #pragma unroll 4
    for (int k = 0; k < HDIM/4; ++k) {
      float4 a = hr[k], b = wr[k];
      s += a.x*b.x + a.y*b.y + a.z*b.z + a.w*b.w;
    }
    st_agent_f32(&pbuf[(size_t)m*ODIM + n], s + bp[n]);
  }

  // ---- one-shot full-grid barrier (pbuf complete), then softmax on blocks < 128 ----
  __syncthreads();
  if (tid == 0)
    __hip_atomic_fetch_add(cnt2 + (jln & 3)*32, 1u, __ATOMIC_RELAXED, __HIP_MEMORY_SCOPE_AGENT);

  if (blockIdx.x >= BDIM) return;

  if (tid == 0) {
    for (;;) {
      unsigned s = 0;
      #pragma unroll
      for (int j = 0; j < 4; ++j)
        s += __hip_atomic_load(cnt2 + j*32, __ATOMIC_RELAXED, __HIP_MEMORY_SCOPE_AGENT);
      if (s >= 256u) break;
      __builtin_amdgcn_s_sleep(1);
    }
    __builtin_amdgcn_fence(__ATOMIC_ACQUIRE, "agent");  // one-shot inv: pbuf readable
  }
  __syncthreads();

  // ---- softmax: one block per batch row (512 thr x float2) ----
  {
    int b = blockIdx.x;
    float* sF = (float*)smem;
    float2 v = ((const float2*)(pbuf + (size_t)b*ODIM))[tid];
    float mx = fmaxf(v.x, v.y);
    #pragma unroll
    for (int off = 32; off > 0; off >>= 1)
      mx = fmaxf(mx, __shfl_xor(mx, off, 64));
    if (lane == 0) sF[wv] = mx;
    __syncthreads();
    mx = sF[0];
    #pragma unroll
    for (int i = 1; i < 8; ++i) mx = fmaxf(mx, sF[i]);
    float e0 = __expf(v.x - mx), e1 = __expf(v.y - mx);
    float s = e0 + e1;
    #pragma unroll
    for (int off = 32; off > 0; off >>= 1)
      s += __shfl_xor(s, off, 64);
    if (lane == 0) sF[8 + wv] = s;
    __syncthreads();
    s = sF[8];
    #pragma unroll
    for (int i = 1; i < 8; ++i) s += sF[8 + i];
    float inv = 1.f / s;
    float2 o; o.x = e0*inv; o.y = e1*inv;
    ((float2*)(out + (size_t)b*ODIM))[tid] = o;
  }
}

// ---------------- host launch ----------------
extern "C" void kernel_launch(void* const* d_in, const int* in_sizes, int n_in,
                              void* d_out, int out_size, void* d_ws, size_t ws_size,
                              hipStream_t stream) {
  (void)in_sizes; (void)n_in; (void)out_size; (void)ws_size;
  const float* x  = (const float*)d_in[0];
  const float* Wx = (const float*)d_in[1];
  const float* bx = (const float*)d_in[2];
  const float* Wh = (const float*)d_in[3];
  const float* Wp = (const float*)d_in[4];
  const float* bp = (const float*)d_in[5];
  float* out = (float*)d_out;
  unsigned char* ws = (unsigned char*)d_ws;

  // zero control block (counters) + h0 slot 0
  hipMemsetAsync(ws, 0, WS_HBUF + BDIM*HDIM*2, stream);

  hipLaunchKernelGGL(prep_kernel, dim3(1024), dim3(256), 0, stream, Wh, Wx, x, ws);

  hipFuncSetAttribute(reinterpret_cast<const void*>(&lstm_main),
                      hipFuncAttributeMaxDynamicSharedMemorySize, SMEM_BYTES);
  void* args[5];
  args[0] = (void*)&bx; args[1] = (void*)&Wp; args[2] = (void*)&bp;
  args[3] = (void*)&ws; args[4] = (void*)&out;
  hipLaunchCooperativeKernel(reinterpret_cast<const void*>(&lstm_main),
                             dim3(256), dim3(512), args, SMEM_BYTES, stream);
}